// Round 1
// baseline (61.301 us; speedup 1.0000x reference)
//
#include <hip/hip_runtime.h>

typedef __bf16 bf16_t;
typedef __attribute__((ext_vector_type(8))) __bf16 bf16x8;
typedef __attribute__((ext_vector_type(16))) float f32x16;
typedef __attribute__((ext_vector_type(2))) float f32x2;
typedef __attribute__((ext_vector_type(2))) unsigned u32x2;
typedef long long i64;
typedef __attribute__((ext_vector_type(2))) long long i64x2;
typedef unsigned long long u64;

#define MFMA32(A, B, C) __builtin_amdgcn_mfma_f32_32x32x16_bf16((A), (B), (C), 0, 0, 0)

// Problem constants: B=8, C=128, H=W=64 -> N=4096, R=16

__device__ __forceinline__ float fexp2(float x) { return __builtin_amdgcn_exp2f(x); }

__device__ __forceinline__ f32x16 mfma_fp8(i64 a, i64 b, f32x16 c) {
  return __builtin_amdgcn_mfma_f32_32x32x16_fp8_fp8(a, b, c, 0, 0, 0);
}
// pack 4 f32 -> 4 fp8(e4m3) bytes
__device__ __forceinline__ unsigned pk4(float a, float b, float c, float d) {
  unsigned u = __builtin_amdgcn_cvt_pk_fp8_f32(a, b, 0u, false);
  return __builtin_amdgcn_cvt_pk_fp8_f32(c, d, u, true);
}
// exchange hi-half of a with lo-half of b (v_permlane32_swap)
__device__ __forceinline__ void swap32(unsigned &a, unsigned &b) {
  asm volatile("v_permlane32_swap_b32 %0, %1" : "+v"(a), "+v"(b));
}
// value of x in partner lane (lane ^ 32)
__device__ __forceinline__ float xhalf(float x, int hi) {
  unsigned a = __builtin_bit_cast(unsigned, x), b = a;
  asm volatile("v_permlane32_swap_b32 %0, %1" : "+v"(a), "+v"(b));
  return __builtin_bit_cast(float, hi ? a : b);
}
__device__ __forceinline__ unsigned pkbf2(float a, float b) {
  union { bf16_t h[2]; unsigned u; } r;
  r.h[0] = (bf16_t)a; r.h[1] = (bf16_t)b;
  return r.u;
}
// packed f32 pair add (VOP3P) — halves the lac reduction instr count
__device__ __forceinline__ f32x2 pkadd(f32x2 a, f32x2 b) {
  f32x2 d;
  asm("v_pk_add_f32 %0, %1, %2" : "=v"(d) : "v"(a), "v"(b));
  return d;
}
__device__ __forceinline__ f32x2 mk2(float a, float b) {
  f32x2 r; r[0] = a; r[1] = b; return r;
}

// -------- kernel 1: fused transpose + q,kT,V-fp8 projections (64-n tiles) --------
// also casts Wo f32 -> bf16 (Wob) for the fused output GEMM.
// q[b][n][r]=QS*(Wq x+bq) (log2-domain); kT[b][m][r]=Wk x+bk;
// vf fp8 fragment-tiled, COALESCED pairs: byte = slot*4096 + (j>>1)*1024 + lane*16 + (j&1)*8
//   fragment (lane,j): V[c=(j&3)*32+(lane&31)][m=slot*32+(j>>2)*16+(lane>>5)*8+e]
__global__ __launch_bounds__(256) void k_qkv(
    const float* __restrict__ x,
    const float* __restrict__ Wq, const float* __restrict__ bq,
    const float* __restrict__ Wk, const float* __restrict__ bk,
    const float* __restrict__ Wv, const float* __restrict__ bv,
    const float* __restrict__ Wo,
    bf16_t* __restrict__ q, bf16_t* __restrict__ kT, char* __restrict__ vfout,
    bf16_t* __restrict__ Wob) {
  __shared__ __align__(16) bf16_t xt[64 * 136];      // [n_loc][c] bf16, stride 272B
  __shared__ __align__(16) bf16_t Wqk_s[32 * 136];
  __shared__ __align__(16) bf16_t Wv_s[128 * 152];   // stride 304B
  __shared__ __align__(8)  char   vst[128 * 72];     // fp8 stage [c][m_loc(64)+8pad]
  const float QS = 0.25f * 1.44269504f;  // scale * log2(e)
  const int b = blockIdx.y;
  const int nb = blockIdx.x;             // 64-col tile
  const int n0 = nb * 64;
  const int t = threadIdx.x;
  if (b == 0) {                          // Wo cast: 64 blocks x 256 = 16384 elems
    int i = nb * 256 + t;
    Wob[i] = (bf16_t)Wo[i];
  }
  for (int i = t; i < 32 * 128; i += 256) {
    int row = i >> 7, col = i & 127;
    float val = (row < 16) ? QS * Wq[row * 128 + col] : Wk[(row - 16) * 128 + col];
    Wqk_s[row * 136 + col] = (bf16_t)val;
  }
  for (int i = t; i < 128 * 128; i += 256)
    Wv_s[(i >> 7) * 152 + (i & 127)] = (bf16_t)Wv[i];

  // ---- one-pass transpose stage: x[c][n] f32 -> xt[n][c] bf16 ----
  const int nl = t & 63, cg = t >> 6;    // thread: n=nl, c-quarter cg
  const float* xb = x + (size_t)b * 524288 + n0 + nl;
  float xv[32];
#pragma unroll
  for (int i = 0; i < 32; ++i) xv[i] = xb[(size_t)(cg * 32 + i) * 4096];
  char* xrow = (char*)xt + nl * 272 + cg * 64;
#pragma unroll
  for (int i = 0; i < 16; ++i)
    *(unsigned*)(xrow + 4 * i) = pkbf2(xv[2 * i], xv[2 * i + 1]);
  __syncthreads();

  const int w = t >> 6, l = t & 63, l31 = l & 31, hi = l >> 5;
  const int nc = w & 1, role = w >> 1;   // waves: 2 n-chunks x 2 roles
  const int nloc = nc * 32 + l31;

  f32x16 aqk;
  f32x16 av[2];
#pragma unroll
  for (int i = 0; i < 16; ++i) { aqk[i] = 0.f; av[0][i] = 0.f; av[1][i] = 0.f; }
#pragma unroll
  for (int kk = 0; kk < 8; ++kk) {
    bf16x8 xf = *(const bf16x8*)((char*)xt + nloc * 272 + kk * 32 + hi * 16);
    if (role == 0) {
      bf16x8 wqk = *(const bf16x8*)(&Wqk_s[l31 * 136 + kk * 16 + 8 * hi]);
      aqk = MFMA32(xf, wqk, aqk);   // D[n][col]: col<16 -> q, col>=16 -> k
    }
#pragma unroll
    for (int j = 0; j < 2; ++j) {
      int ct = role * 2 + j;
      bf16x8 wvv = *(const bf16x8*)(&Wv_s[(ct * 32 + l31) * 152 + kk * 16 + 8 * hi]);
      av[j] = MFMA32(wvv, xf, av[j]);  // D[c_out][n]
    }
  }
  if (role == 0) {
    const float bias_qk = (l31 < 16) ? QS * bq[l31] : bk[l31 - 16];
#pragma unroll
    for (int r = 0; r < 16; ++r) {
      int n = n0 + nc * 32 + (r & 3) + 8 * (r >> 2) + 4 * hi;
      bf16_t vb16 = (bf16_t)(aqk[r] + bias_qk);
      if (l31 < 16) q[((size_t)(b * 4096 + n)) * 16 + l31] = vb16;
      else          kT[((size_t)(b * 4096 + n)) * 16 + (l31 - 16)] = vb16;
    }
  }

  // ---- v epilogue: fp8 convert -> vst[c][m_loc], then fragment-tiled vf ----
  const int mloc = nc * 32 + l31;
#pragma unroll
  for (int j = 0; j < 2; ++j) {
    int ct = role * 2 + j;
#pragma unroll
    for (int r = 0; r < 16; r += 2) {
      int c = ct * 32 + (r & 3) + 8 * (r >> 2) + 4 * hi;
      unsigned pw = pk4(av[j][r] + bv[c], av[j][r + 1] + bv[c + 1], 0.f, 0.f);
      vst[c * 72 + mloc] = (char)(pw & 0xff);
      vst[(c + 1) * 72 + mloc] = (char)((pw >> 8) & 0xff);
    }
  }
  __syncthreads();
  char* vfb = vfout + (size_t)b * 524288 + (size_t)nb * 8192;
#pragma unroll
  for (int it = 0; it < 4; ++it) {
    int id = t + 256 * it;               // 0..1023
    int jj = id & 7, ln = (id >> 3) & 63, sl = id >> 9;
    int half = jj >> 2, ct = jj & 3;
    int c = ct * 32 + (ln & 31);
    int m0 = sl * 32 + half * 16 + (ln >> 5) * 8;
    u64 v8 = *(const u64*)(vst + c * 72 + m0);
    *(u64*)(vfb + (size_t)sl * 4096 + (size_t)(jj >> 1) * 1024 + (size_t)ln * 16 + (jj & 1) * 8) = v8;
  }
}

// -------- kernel 2: flash attention (R7 order) + fused Wo epilogue --------
// 512 blocks = 8 batch x 64 q-blocks(64q). 8 waves = 2 q-chunks x 4 m-quarters.
// Waves sharing an m-quarter read identical V/K addresses (L1 dedup).
// R10 convoy-breakers (loop ORDER unchanged — R8/R9 reorder regressed via spills):
//   (a) s_setprio(1) around the PV MFMA cluster: waves in PV phase win issue
//       arbitration over waves in exp phase -> matrix/VALU phases interleave
//       across the 4 resident waves instead of oscillating in lockstep.
//   (b) one-time s_sleep stagger for waves 4-7 seeds the phase offset.
//   (c) v_pk_add_f32 lac tree: 15 adds -> 8 packed ops, shorter serial chain.
__global__ __launch_bounds__(512, 4) void k_attn(
    const bf16_t* __restrict__ q, const bf16_t* __restrict__ kT,
    const char* __restrict__ vf, const bf16_t* __restrict__ Wob,
    const float* __restrict__ bo, const float* __restrict__ gammap,
    const float* __restrict__ x, float* __restrict__ out) {
  __shared__ __align__(16) bf16_t accb[8][32][136];  // 69.6 KB
  __shared__ float lsum[8][32];
  __shared__ float linv[64];
  const int bid = blockIdx.x;
  const int b = bid & 7, qb = bid >> 3;   // batch-in-low-bits -> XCD/L2 affinity
  const int t = threadIdx.x, w = t >> 6, l = t & 63, l31 = l & 31, hi = l >> 5;
  const int qg = w & 1, mq = w >> 1;
  const int n0 = qb * 64 + qg * 32;

  // de-phase the two co-SIMD waves of this block (one-time, ~1k cyc)
  if (w & 4) __builtin_amdgcn_s_sleep(16);

  const bf16_t* kw = kT + (size_t)b * 65536 + (size_t)mq * 16384;
  const char* vw = vf + (size_t)b * 524288 + (size_t)mq * 131072 + (size_t)l * 16;

  bf16x8 qf = *(const bf16x8*)(q + ((size_t)(b * 4096) + n0 + l31) * 16 + 8 * hi);
  bf16x8 kf = *(const bf16x8*)(kw + (size_t)l31 * 16 + 8 * hi);

  f32x16 z;
#pragma unroll
  for (int i = 0; i < 16; ++i) z[i] = 0.f;
  f32x16 acc[4];
#pragma unroll
  for (int ct = 0; ct < 4; ++ct) acc[ct] = z;
  f32x2 lacc = mk2(0.f, 0.f);

#pragma unroll 2
  for (int s = 0; s < 32; ++s) {
    const char* vt = vw + (size_t)s * 4096;
    i64x2 va2[4];
#pragma unroll
    for (int p = 0; p < 4; ++p) va2[p] = *(const i64x2*)(vt + p * 1024);

    f32x16 st = MFMA32(kf, qf, z);   // D[m][n]: m=(r&3)+8(r>>2)+4hi, n=l31
    kf = *(const bf16x8*)(kw + ((size_t)((s + 1) * 32 + l31)) * 16 + 8 * hi);

    float p[16];
#pragma unroll
    for (int i = 0; i < 16; ++i) p[i] = fexp2(st[i]);   // no-max softmax (bounded scores)

    // packed lac tree: 8 pk-adds replace 15 scalar adds
    f32x2 t0 = pkadd(mk2(p[0], p[1]), mk2(p[2], p[3]));
    f32x2 t1 = pkadd(mk2(p[4], p[5]), mk2(p[6], p[7]));
    f32x2 t2 = pkadd(mk2(p[8], p[9]), mk2(p[10], p[11]));
    f32x2 t3 = pkadd(mk2(p[12], p[13]), mk2(p[14], p[15]));
    lacc = pkadd(lacc, pkadd(pkadd(t0, t1), pkadd(t2, t3)));

    // pack p -> fp8 operands; swap32 pairing leaves {w0,w1}=m0..15, {w2,w3}=m16..31
    unsigned w0 = pk4(p[0], p[1], p[2], p[3]);
    unsigned w1 = pk4(p[4], p[5], p[6], p[7]);
    unsigned w2 = pk4(p[8], p[9], p[10], p[11]);
    unsigned w3 = pk4(p[12], p[13], p[14], p[15]);
    swap32(w0, w1);
    swap32(w2, w3);
    u32x2 A, Bv;
    A[0] = w0; A[1] = w1;
    Bv[0] = w2; Bv[1] = w3;
    i64 pA = __builtin_bit_cast(i64, A);
    i64 pB = __builtin_bit_cast(i64, Bv);

    __builtin_amdgcn_s_setprio(1);
#pragma unroll
    for (int ct = 0; ct < 4; ++ct) acc[ct] = mfma_fp8(va2[ct >> 1][ct & 1], pA, acc[ct]);
#pragma unroll
    for (int ct = 0; ct < 4; ++ct) acc[ct] = mfma_fp8(va2[2 + (ct >> 1)][ct & 1], pB, acc[ct]);
    __builtin_amdgcn_s_setprio(0);
  }
  float lac = lacc[0] + lacc[1];

  // ---- cross-mq combine (sum of partials) ----
  float lT = lac + xhalf(lac, hi);
  if (hi == 0) lsum[w][l31] = lT;
#pragma unroll
  for (int ct = 0; ct < 4; ++ct) {
#pragma unroll
    for (int g = 0; g < 4; ++g) {
      union { unsigned short h[4]; u64 u; } pw;
#pragma unroll
      for (int j = 0; j < 4; ++j) {
        bf16_t bb = (bf16_t)acc[ct][g * 4 + j];
        pw.h[j] = __builtin_bit_cast(unsigned short, bb);
      }
      *(u64*)&accb[w][l31][ct * 32 + 8 * g + 4 * hi] = pw.u;
    }
  }
  __syncthreads();

  {
    const int rn64 = t >> 3;            // 0..63 : local n
    const int qg2 = rn64 >> 5, rn = rn64 & 31;
    const int c0 = (t & 7) * 16;
    float L = (lsum[qg2][rn] + lsum[qg2 + 2][rn]) + (lsum[qg2 + 4][rn] + lsum[qg2 + 6][rn]);
    if ((t & 7) == 0) linv[rn64] = 1.0f / L;
    float o[16];
#pragma unroll
    for (int i = 0; i < 16; ++i) o[i] = 0.f;
#pragma unroll
    for (int m2 = 0; m2 < 4; ++m2) {
#pragma unroll
      for (int h2 = 0; h2 < 2; ++h2) {
        bf16x8 ch = *(const bf16x8*)&accb[qg2 + 2 * m2][rn][c0 + h2 * 8];
#pragma unroll
        for (int e = 0; e < 8; ++e) o[h2 * 8 + e] += (float)ch[e];
      }
    }
    // write combined RAW (unnormalized) back into accb[qg2][rn][c0..c0+15]
#pragma unroll
    for (int h2 = 0; h2 < 2; ++h2) {
      bf16x8 sv;
#pragma unroll
      for (int e = 0; e < 8; ++e) sv[e] = (bf16_t)o[h2 * 8 + e];
      *(bf16x8*)&accb[qg2][rn][c0 + h2 * 8] = sv;
    }
  }
  __syncthreads();

  // ---- fused output projection: out = gamma*(Wo @ attn + bo) + x ----
  // out is stream-once -> NT store (no L2 allocate); x load stays cached.
  {
    const int obk = w >> 1, nh = w & 1;
    const int o0 = obk * 32;
    f32x16 oc;
#pragma unroll
    for (int i = 0; i < 16; ++i) oc[i] = 0.f;
#pragma unroll
    for (int kk = 0; kk < 8; ++kk) {
      bf16x8 wof = *(const bf16x8*)(Wob + (size_t)(o0 + l31) * 128 + kk * 16 + 8 * hi);
      bf16x8 cf = *(const bf16x8*)&accb[nh][l31][kk * 16 + 8 * hi];
      oc = MFMA32(wof, cf, oc);  // D[o][n], n = l31
    }
    const float g = gammap[0];
    const float iv = linv[nh * 32 + l31];
    const int ng = qb * 64 + nh * 32 + l31;
#pragma unroll
    for (int r = 0; r < 16; ++r) {
      int o_ = o0 + (r & 3) + 8 * (r >> 2) + 4 * hi;
      size_t off = ((size_t)(b * 128 + o_)) * 4096 + ng;
      __builtin_nontemporal_store(g * (oc[r] * iv + bo[o_]) + x[off], &out[off]);
    }
  }
}

extern "C" void kernel_launch(void* const* d_in, const int* in_sizes, int n_in,
                              void* d_out, int out_size, void* d_ws, size_t ws_size,
                              hipStream_t stream) {
  const float* x  = (const float*)d_in[0];
  const float* Wq = (const float*)d_in[1];
  const float* bq = (const float*)d_in[2];
  const float* Wk = (const float*)d_in[3];
  const float* bk = (const float*)d_in[4];
  const float* Wv = (const float*)d_in[5];
  const float* bv = (const float*)d_in[6];
  const float* Wo = (const float*)d_in[7];
  const float* bo = (const float*)d_in[8];
  const float* gm = (const float*)d_in[9];
  float* out = (float*)d_out;

  char* ws = (char*)d_ws;
  bf16_t* q   = (bf16_t*)(ws);                        // 1 MB [B][N][16]
  bf16_t* kT  = (bf16_t*)(ws + (size_t)(1 << 20));    // 1 MB [B][N][16]
  char*   vf  = (char*)  (ws + (size_t)(2 << 20));    // 4 MB fp8 fragment-tiled V
  bf16_t* Wob = (bf16_t*)(ws + (size_t)(6 << 20));    // 32 KB Wo bf16

  k_qkv<<<dim3(64, 8), 256, 0, stream>>>(x, Wq, bq, Wk, bk, Wv, bv, Wo, q, kT, vf, Wob);
  k_attn<<<512, 512, 0, stream>>>(q, kT, vf, Wob, bo, gm, x, out);
}

// Round 2
// 59.088 us; speedup vs baseline: 1.0375x; 1.0375x over previous
//
#include <hip/hip_runtime.h>

typedef __bf16 bf16_t;
typedef __attribute__((ext_vector_type(8))) __bf16 bf16x8;
typedef __attribute__((ext_vector_type(16))) float f32x16;
typedef __attribute__((ext_vector_type(2))) unsigned u32x2;
typedef long long i64;
typedef __attribute__((ext_vector_type(2))) long long i64x2;
typedef unsigned long long u64;

#define MFMA32(A, B, C) __builtin_amdgcn_mfma_f32_32x32x16_bf16((A), (B), (C), 0, 0, 0)

// Problem constants: B=8, C=128, H=W=64 -> N=4096, R=16

__device__ __forceinline__ float fexp2(float x) { return __builtin_amdgcn_exp2f(x); }

__device__ __forceinline__ f32x16 mfma_fp8(i64 a, i64 b, f32x16 c) {
  return __builtin_amdgcn_mfma_f32_32x32x16_fp8_fp8(a, b, c, 0, 0, 0);
}
// pack 4 f32 -> 4 fp8(e4m3) bytes
__device__ __forceinline__ unsigned pk4(float a, float b, float c, float d) {
  unsigned u = __builtin_amdgcn_cvt_pk_fp8_f32(a, b, 0u, false);
  return __builtin_amdgcn_cvt_pk_fp8_f32(c, d, u, true);
}
// exchange hi-half of a with lo-half of b (v_permlane32_swap)
__device__ __forceinline__ void swap32(unsigned &a, unsigned &b) {
  asm volatile("v_permlane32_swap_b32 %0, %1" : "+v"(a), "+v"(b));
}
// value of x in partner lane (lane ^ 32)
__device__ __forceinline__ float xhalf(float x, int hi) {
  unsigned a = __builtin_bit_cast(unsigned, x), b = a;
  asm volatile("v_permlane32_swap_b32 %0, %1" : "+v"(a), "+v"(b));
  return __builtin_bit_cast(float, hi ? a : b);
}
__device__ __forceinline__ unsigned pkbf2(float a, float b) {
  union { bf16_t h[2]; unsigned u; } r;
  r.h[0] = (bf16_t)a; r.h[1] = (bf16_t)b;
  return r.u;
}
// async global->LDS, 16B per lane (lds dest is wave-uniform base + lane*16)
__device__ __forceinline__ void gl_lds16(const void* g, void* l) {
  __builtin_amdgcn_global_load_lds(
      (const __attribute__((address_space(1))) void*)g,
      (__attribute__((address_space(3))) void*)l, 16, 0, 0);
}

// -------- kernel 1: fused transpose + q,kT,V-fp8 projections (64-n tiles) --------
// also casts Wo f32 -> bf16 (Wob) for the fused output GEMM.
// q[b][n][r]=QS*(Wq x+bq) (log2-domain); kT[b][m][r]=Wk x+bk;
// vf fp8 fragment-tiled, COALESCED pairs: byte = slot*4096 + (j>>1)*1024 + lane*16 + (j&1)*8
//   fragment (lane,j): V[c=(j&3)*32+(lane&31)][m=slot*32+(j>>2)*16+(lane>>5)*8+e]
__global__ __launch_bounds__(256) void k_qkv(
    const float* __restrict__ x,
    const float* __restrict__ Wq, const float* __restrict__ bq,
    const float* __restrict__ Wk, const float* __restrict__ bk,
    const float* __restrict__ Wv, const float* __restrict__ bv,
    const float* __restrict__ Wo,
    bf16_t* __restrict__ q, bf16_t* __restrict__ kT, char* __restrict__ vfout,
    bf16_t* __restrict__ Wob) {
  __shared__ __align__(16) bf16_t xt[64 * 136];      // [n_loc][c] bf16, stride 272B
  __shared__ __align__(16) bf16_t Wqk_s[32 * 136];
  __shared__ __align__(16) bf16_t Wv_s[128 * 152];   // stride 304B
  __shared__ __align__(8)  char   vst[128 * 72];     // fp8 stage [c][m_loc(64)+8pad]
  const float QS = 0.25f * 1.44269504f;  // scale * log2(e)
  const int b = blockIdx.y;
  const int nb = blockIdx.x;             // 64-col tile
  const int n0 = nb * 64;
  const int t = threadIdx.x;
  if (b == 0) {                          // Wo cast: 64 blocks x 256 = 16384 elems
    int i = nb * 256 + t;
    Wob[i] = (bf16_t)Wo[i];
  }
  for (int i = t; i < 32 * 128; i += 256) {
    int row = i >> 7, col = i & 127;
    float val = (row < 16) ? QS * Wq[row * 128 + col] : Wk[(row - 16) * 128 + col];
    Wqk_s[row * 136 + col] = (bf16_t)val;
  }
  for (int i = t; i < 128 * 128; i += 256)
    Wv_s[(i >> 7) * 152 + (i & 127)] = (bf16_t)Wv[i];

  // ---- one-pass transpose stage: x[c][n] f32 -> xt[n][c] bf16 ----
  const int nl = t & 63, cg = t >> 6;    // thread: n=nl, c-quarter cg
  const float* xb = x + (size_t)b * 524288 + n0 + nl;
  float xv[32];
#pragma unroll
  for (int i = 0; i < 32; ++i) xv[i] = xb[(size_t)(cg * 32 + i) * 4096];
  char* xrow = (char*)xt + nl * 272 + cg * 64;
#pragma unroll
  for (int i = 0; i < 16; ++i)
    *(unsigned*)(xrow + 4 * i) = pkbf2(xv[2 * i], xv[2 * i + 1]);
  __syncthreads();

  const int w = t >> 6, l = t & 63, l31 = l & 31, hi = l >> 5;
  const int nc = w & 1, role = w >> 1;   // waves: 2 n-chunks x 2 roles
  const int nloc = nc * 32 + l31;

  f32x16 aqk;
  f32x16 av[2];
#pragma unroll
  for (int i = 0; i < 16; ++i) { aqk[i] = 0.f; av[0][i] = 0.f; av[1][i] = 0.f; }
#pragma unroll
  for (int kk = 0; kk < 8; ++kk) {
    bf16x8 xf = *(const bf16x8*)((char*)xt + nloc * 272 + kk * 32 + hi * 16);
    if (role == 0) {
      bf16x8 wqk = *(const bf16x8*)(&Wqk_s[l31 * 136 + kk * 16 + 8 * hi]);
      aqk = MFMA32(xf, wqk, aqk);   // D[n][col]: col<16 -> q, col>=16 -> k
    }
#pragma unroll
    for (int j = 0; j < 2; ++j) {
      int ct = role * 2 + j;
      bf16x8 wvv = *(const bf16x8*)(&Wv_s[(ct * 32 + l31) * 152 + kk * 16 + 8 * hi]);
      av[j] = MFMA32(wvv, xf, av[j]);  // D[c_out][n]
    }
  }
  if (role == 0) {
    const float bias_qk = (l31 < 16) ? QS * bq[l31] : bk[l31 - 16];
#pragma unroll
    for (int r = 0; r < 16; ++r) {
      int n = n0 + nc * 32 + (r & 3) + 8 * (r >> 2) + 4 * hi;
      bf16_t vb16 = (bf16_t)(aqk[r] + bias_qk);
      if (l31 < 16) q[((size_t)(b * 4096 + n)) * 16 + l31] = vb16;
      else          kT[((size_t)(b * 4096 + n)) * 16 + (l31 - 16)] = vb16;
    }
  }

  // ---- v epilogue: fp8 convert -> vst[c][m_loc], then fragment-tiled vf ----
  const int mloc = nc * 32 + l31;
#pragma unroll
  for (int j = 0; j < 2; ++j) {
    int ct = role * 2 + j;
#pragma unroll
    for (int r = 0; r < 16; r += 2) {
      int c = ct * 32 + (r & 3) + 8 * (r >> 2) + 4 * hi;
      unsigned pw = pk4(av[j][r] + bv[c], av[j][r + 1] + bv[c + 1], 0.f, 0.f);
      vst[c * 72 + mloc] = (char)(pw & 0xff);
      vst[(c + 1) * 72 + mloc] = (char)((pw >> 8) & 0xff);
    }
  }
  __syncthreads();
  char* vfb = vfout + (size_t)b * 524288 + (size_t)nb * 8192;
#pragma unroll
  for (int it = 0; it < 4; ++it) {
    int id = t + 256 * it;               // 0..1023
    int jj = id & 7, ln = (id >> 3) & 63, sl = id >> 9;
    int half = jj >> 2, ct = jj & 3;
    int c = ct * 32 + (ln & 31);
    int m0 = sl * 32 + half * 16 + (ln >> 5) * 8;
    u64 v8 = *(const u64*)(vst + c * 72 + m0);
    *(u64*)(vfb + (size_t)sl * 4096 + (size_t)(jj >> 1) * 1024 + (size_t)ln * 16 + (jj & 1) * 8) = v8;
  }
}

// -------- kernel 2: flash attention + fused Wo epilogue --------
// 512 blocks = 8 batch x 64 q-blocks(64q). 8 waves = 2 q-chunks x 4 m-quarters.
// R11: V staged through LDS (depth-3 ring, 48KB ALIASED over the accb scratch,
// which is dead during the main loop). Rationale: at 64 arch VGPRs the compiler
// can't keep two steps' V operands live, so V global loads were consumed
// same-step -> ~200-400cy exposed L2 latency stalled all 4 resident waves
// (3530 cyc/step/SIMD vs ~1160 of issue work). global_load_lds costs no data
// VGPRs, stages step s+2 at step s (a full step of latency lead), and the
// per-step __syncthreads drain is free because the loads it waits on were
// issued ~1000cy earlier. Also de-duplicates V across qg wave-pairs.
// Depth 3 (not 2) so the buffer written at step s was last read at step s-1,
// strictly before the barrier every wave passed -> race-free by construction.
__global__ __launch_bounds__(512, 4) void k_attn(
    const bf16_t* __restrict__ q, const bf16_t* __restrict__ kT,
    const char* __restrict__ vf, const bf16_t* __restrict__ Wob,
    const float* __restrict__ bo, const float* __restrict__ gammap,
    const float* __restrict__ x, float* __restrict__ out) {
  __shared__ __align__(16) bf16_t accb[8][32][136];  // 69.6 KB (aliased: V ring 48KB in main loop)
  __shared__ float lsum[8][32];
  __shared__ float linv[64];
  const int bid = blockIdx.x;
  const int b = bid & 7, qb = bid >> 3;   // batch-in-low-bits -> XCD/L2 affinity
  const int t = threadIdx.x, w = t >> 6, l = t & 63, l31 = l & 31, hi = l >> 5;
  const int qg = w & 1, mq = w >> 1;
  const int n0 = qb * 64 + qg * 32;

  const bf16_t* kw = kT + (size_t)b * 65536 + (size_t)mq * 16384;

  bf16x8 qf = *(const bf16x8*)(q + ((size_t)(b * 4096) + n0 + l31) * 16 + 8 * hi);
  bf16x8 kf = *(const bf16x8*)(kw + (size_t)l31 * 16 + 8 * hi);

  // ---- V LDS ring setup ----
  // block needs 16KB/step (4 mq x 4KB, de-duplicated); 16 chunks of 1KB;
  // wave w stages chunks 2w, 2w+1.
  char* const vls = (char*)&accb[0][0][0];
  char* r0 = vls;                // read buffer  (step s)
  char* r1 = vls + 16384;        // next         (step s+1)
  char* r2 = vls + 32768;        // stage target (step s+2)
  const char* vsrc = vf + (size_t)b * 524288;
  const int ch0 = w * 2, ch1 = w * 2 + 1;
  const size_t go0 = (size_t)(ch0 >> 2) * 131072 + (size_t)(ch0 & 3) * 1024 + (size_t)l * 16;
  const size_t go1 = (size_t)(ch1 >> 2) * 131072 + (size_t)(ch1 & 3) * 1024 + (size_t)l * 16;
  const int lo0 = (ch0 >> 2) * 4096 + (ch0 & 3) * 1024;
  const int lo1 = (ch1 >> 2) * 4096 + (ch1 & 3) * 1024;
  // prologue: stage steps 0 and 1
  gl_lds16(vsrc + go0, r0 + lo0);
  gl_lds16(vsrc + go1, r0 + lo1);
  gl_lds16(vsrc + go0 + 4096, r1 + lo0);
  gl_lds16(vsrc + go1 + 4096, r1 + lo1);

  f32x16 z;
#pragma unroll
  for (int i = 0; i < 16; ++i) z[i] = 0.f;
  f32x16 acc[4];
#pragma unroll
  for (int ct = 0; ct < 4; ++ct) acc[ct] = z;
  float lac = 0.f;

#pragma unroll 2
  for (int s = 0; s < 32; ++s) {
    __syncthreads();                     // stage(s) landed in r0 & visible; all waves past their s-1 reads
    const char* vt = r0 + mq * 4096 + (size_t)l * 16;
    i64x2 va2[4];
#pragma unroll
    for (int pp = 0; pp < 4; ++pp) va2[pp] = *(const i64x2*)(vt + pp * 1024);

    if (s < 30) {                        // stage s+2 into r2 (last read at s-1: race-free)
      size_t go = (size_t)(s + 2) * 4096;
      gl_lds16(vsrc + go0 + go, r2 + lo0);
      gl_lds16(vsrc + go1 + go, r2 + lo1);
    }

    f32x16 st = MFMA32(kf, qf, z);   // D[m][n]: m=(r&3)+8(r>>2)+4hi, n=l31
    kf = *(const bf16x8*)(kw + ((size_t)((s + 1) * 32 + l31)) * 16 + 8 * hi);

    float p[16];
#pragma unroll
    for (int i = 0; i < 16; ++i) p[i] = fexp2(st[i]);   // no-max softmax (bounded scores)
    float s0 = (p[0] + p[1]) + (p[2] + p[3]), s1 = (p[4] + p[5]) + (p[6] + p[7]);
    float s2 = (p[8] + p[9]) + (p[10] + p[11]), s3 = (p[12] + p[13]) + (p[14] + p[15]);
    lac += (s0 + s1) + (s2 + s3);

    // pack p -> fp8 operands; swap32 pairing leaves {w0,w1}=m0..15, {w2,w3}=m16..31
    unsigned w0 = pk4(p[0], p[1], p[2], p[3]);
    unsigned w1 = pk4(p[4], p[5], p[6], p[7]);
    unsigned w2 = pk4(p[8], p[9], p[10], p[11]);
    unsigned w3 = pk4(p[12], p[13], p[14], p[15]);
    swap32(w0, w1);
    swap32(w2, w3);
    u32x2 A, Bv;
    A[0] = w0; A[1] = w1;
    Bv[0] = w2; Bv[1] = w3;
    i64 pA = __builtin_bit_cast(i64, A);
    i64 pB = __builtin_bit_cast(i64, Bv);

#pragma unroll
    for (int ct = 0; ct < 4; ++ct) acc[ct] = mfma_fp8(va2[ct >> 1][ct & 1], pA, acc[ct]);
#pragma unroll
    for (int ct = 0; ct < 4; ++ct) acc[ct] = mfma_fp8(va2[2 + (ct >> 1)][ct & 1], pB, acc[ct]);

    char* tmp = r0; r0 = r1; r1 = r2; r2 = tmp;   // rotate ring
  }
  __syncthreads();   // all waves done reading V ring before accb overwrites it

  // ---- cross-mq combine (sum of partials) ----
  float lT = lac + xhalf(lac, hi);
  if (hi == 0) lsum[w][l31] = lT;
#pragma unroll
  for (int ct = 0; ct < 4; ++ct) {
#pragma unroll
    for (int g = 0; g < 4; ++g) {
      union { unsigned short h[4]; u64 u; } pw;
#pragma unroll
      for (int j = 0; j < 4; ++j) {
        bf16_t bb = (bf16_t)acc[ct][g * 4 + j];
        pw.h[j] = __builtin_bit_cast(unsigned short, bb);
      }
      *(u64*)&accb[w][l31][ct * 32 + 8 * g + 4 * hi] = pw.u;
    }
  }
  __syncthreads();

  {
    const int rn64 = t >> 3;            // 0..63 : local n
    const int qg2 = rn64 >> 5, rn = rn64 & 31;
    const int c0 = (t & 7) * 16;
    float L = (lsum[qg2][rn] + lsum[qg2 + 2][rn]) + (lsum[qg2 + 4][rn] + lsum[qg2 + 6][rn]);
    if ((t & 7) == 0) linv[rn64] = 1.0f / L;
    float o[16];
#pragma unroll
    for (int i = 0; i < 16; ++i) o[i] = 0.f;
#pragma unroll
    for (int m2 = 0; m2 < 4; ++m2) {
#pragma unroll
      for (int h2 = 0; h2 < 2; ++h2) {
        bf16x8 ch = *(const bf16x8*)&accb[qg2 + 2 * m2][rn][c0 + h2 * 8];
#pragma unroll
        for (int e = 0; e < 8; ++e) o[h2 * 8 + e] += (float)ch[e];
      }
    }
    // write combined RAW (unnormalized) back into accb[qg2][rn][c0..c0+15]
#pragma unroll
    for (int h2 = 0; h2 < 2; ++h2) {
      bf16x8 sv;
#pragma unroll
      for (int e = 0; e < 8; ++e) sv[e] = (bf16_t)o[h2 * 8 + e];
      *(bf16x8*)&accb[qg2][rn][c0 + h2 * 8] = sv;
    }
  }
  __syncthreads();

  // ---- fused output projection: out = gamma*(Wo @ attn + bo) + x ----
  // out is stream-once -> NT store (no L2 allocate); x load stays cached.
  {
    const int obk = w >> 1, nh = w & 1;
    const int o0 = obk * 32;
    f32x16 oc;
#pragma unroll
    for (int i = 0; i < 16; ++i) oc[i] = 0.f;
#pragma unroll
    for (int kk = 0; kk < 8; ++kk) {
      bf16x8 wof = *(const bf16x8*)(Wob + (size_t)(o0 + l31) * 128 + kk * 16 + 8 * hi);
      bf16x8 cf = *(const bf16x8*)&accb[nh][l31][kk * 16 + 8 * hi];
      oc = MFMA32(wof, cf, oc);  // D[o][n], n = l31
    }
    const float g = gammap[0];
    const float iv = linv[nh * 32 + l31];
    const int ng = qb * 64 + nh * 32 + l31;
#pragma unroll
    for (int r = 0; r < 16; ++r) {
      int o_ = o0 + (r & 3) + 8 * (r >> 2) + 4 * hi;
      size_t off = ((size_t)(b * 128 + o_)) * 4096 + ng;
      __builtin_nontemporal_store(g * (oc[r] * iv + bo[o_]) + x[off], &out[off]);
    }
  }
}

extern "C" void kernel_launch(void* const* d_in, const int* in_sizes, int n_in,
                              void* d_out, int out_size, void* d_ws, size_t ws_size,
                              hipStream_t stream) {
  const float* x  = (const float*)d_in[0];
  const float* Wq = (const float*)d_in[1];
  const float* bq = (const float*)d_in[2];
  const float* Wk = (const float*)d_in[3];
  const float* bk = (const float*)d_in[4];
  const float* Wv = (const float*)d_in[5];
  const float* bv = (const float*)d_in[6];
  const float* Wo = (const float*)d_in[7];
  const float* bo = (const float*)d_in[8];
  const float* gm = (const float*)d_in[9];
  float* out = (float*)d_out;

  char* ws = (char*)d_ws;
  bf16_t* q   = (bf16_t*)(ws);                        // 1 MB [B][N][16]
  bf16_t* kT  = (bf16_t*)(ws + (size_t)(1 << 20));    // 1 MB [B][N][16]
  char*   vf  = (char*)  (ws + (size_t)(2 << 20));    // 4 MB fp8 fragment-tiled V
  bf16_t* Wob = (bf16_t*)(ws + (size_t)(6 << 20));    // 32 KB Wo bf16

  k_qkv<<<dim3(64, 8), 256, 0, stream>>>(x, Wq, bq, Wk, bk, Wv, bv, Wo, q, kT, vf, Wob);
  k_attn<<<512, 512, 0, stream>>>(q, kT, vf, Wob, bo, gm, x, out);
}